// Round 1
// baseline (63.853 us; speedup 1.0000x reference)
//
#include <hip/hip_runtime.h>

#define HH 360
#define WW 480
#define NG 256
#define NPIX (HH * WW)          // 172800, divisible by 256 -> 675 blocks
#define ALPHA_MIN (1.0f / 255.0f)
#define ALPHA_MAX 0.99f

// ---------------------------------------------------------------------------
// Kernel 1: stable depth sort (rank via O(N^2) comparisons, N=256) and
// scatter into SoA layout in workspace:
//   ws[0*NG..]=ca  ws[1*NG..]=cb  ws[2*NG..]=cc  ws[3*NG..]=opacity
//   ws[4*NG..]=r   ws[5*NG..]=g   ws[6*NG..]=b   ws[7*NG..]=depth
//   ws[8*NG..]=mx  ws[9*NG..]=my
// ---------------------------------------------------------------------------
__global__ __launch_bounds__(NG) void gs_sort_kernel(
    const float* __restrict__ md,      // (NG, 8)
    const float* __restrict__ means,   // (NG, 2)
    float* __restrict__ ws)            // (10, NG)
{
    __shared__ float sdep[NG];
    const int i = threadIdx.x;
    const float d = md[i * 8 + 7];
    sdep[i] = d;
    __syncthreads();

    // stable rank: count strictly-smaller, plus equal-with-lower-index
    int rank = 0;
    #pragma unroll 8
    for (int j = 0; j < NG; ++j) {
        const float dj = sdep[j];
        rank += (dj < d) || ((dj == d) && (j < i));
    }

    ws[0 * NG + rank] = md[i * 8 + 4];   // ca
    ws[1 * NG + rank] = md[i * 8 + 5];   // cb
    ws[2 * NG + rank] = md[i * 8 + 6];   // cc
    ws[3 * NG + rank] = md[i * 8 + 3];   // opacity
    ws[4 * NG + rank] = md[i * 8 + 0];   // color r
    ws[5 * NG + rank] = md[i * 8 + 1];   // color g
    ws[6 * NG + rank] = md[i * 8 + 2];   // color b
    ws[7 * NG + rank] = d;               // depth
    ws[8 * NG + rank] = means[i * 2 + 0];
    ws[9 * NG + rank] = means[i * 2 + 1];
}

// ---------------------------------------------------------------------------
// Kernel 2: per-pixel sequential alpha compositing over sorted gaussians.
// One thread = one pixel. Sorted SoA staged in LDS (10 KB); every iteration
// all 64 lanes read the SAME LDS address -> broadcast, no bank conflicts.
// ---------------------------------------------------------------------------
__global__ __launch_bounds__(256) void gs_raster_kernel(
    const float* __restrict__ ws,
    float* __restrict__ out)
{
    __shared__ float s[10 * NG];
    for (int k = threadIdx.x; k < 10 * NG; k += 256) s[k] = ws[k];
    __syncthreads();

    const int p = blockIdx.x * 256 + threadIdx.x;   // grid sized exactly
    const int h = p / WW;
    const int w = p - h * WW;
    const float x = (float)w + 0.5f;
    const float y = (float)h + 0.5f;

    const float* __restrict__ ca = s + 0 * NG;
    const float* __restrict__ cb = s + 1 * NG;
    const float* __restrict__ cc = s + 2 * NG;
    const float* __restrict__ op = s + 3 * NG;
    const float* __restrict__ cr = s + 4 * NG;
    const float* __restrict__ cg = s + 5 * NG;
    const float* __restrict__ cbl = s + 6 * NG;
    const float* __restrict__ dz = s + 7 * NG;
    const float* __restrict__ mx = s + 8 * NG;
    const float* __restrict__ my = s + 9 * NG;

    float T = 1.0f;
    float accR = 0.0f, accG = 0.0f, accB = 0.0f, accD = 0.0f;

    #pragma unroll 4
    for (int i = 0; i < NG; ++i) {
        const float dx = x - mx[i];
        const float dy = y - my[i];
        const float power = -0.5f * (ca[i] * dx * dx + cc[i] * dy * dy)
                            - cb[i] * dx * dy;
        float alpha = 0.0f;
        if (power <= 0.0f) {
            alpha = fminf(op[i] * __expf(power), ALPHA_MAX);
            if (alpha < ALPHA_MIN) alpha = 0.0f;
        }
        const float wgt = alpha * T;
        accR += wgt * cr[i];
        accG += wgt * cg[i];
        accB += wgt * cbl[i];
        accD += wgt * dz[i];
        T *= (1.0f - alpha);
    }

    // outputs concatenated flat: color (H,W,3) | depth (H,W,1) | sil (H,W,1)
    out[p * 3 + 0] = accR;
    out[p * 3 + 1] = accG;
    out[p * 3 + 2] = accB;
    out[NPIX * 3 + p] = accD;
    out[NPIX * 4 + p] = 1.0f - T;
}

extern "C" void kernel_launch(void* const* d_in, const int* in_sizes, int n_in,
                              void* d_out, int out_size, void* d_ws, size_t ws_size,
                              hipStream_t stream) {
    const float* md    = (const float*)d_in[0];   // md_1_for (256,8)
    const float* means = (const float*)d_in[1];   // means2D  (256,2)
    float* out = (float*)d_out;
    float* ws  = (float*)d_ws;                    // needs 10*256*4 = 10240 B

    gs_sort_kernel<<<1, NG, 0, stream>>>(md, means, ws);
    gs_raster_kernel<<<NPIX / 256, 256, 0, stream>>>(ws, out);
}

// Round 2
// 17.287 us; speedup vs baseline: 3.6937x; 3.6937x over previous
//
#include <hip/hip_runtime.h>

#define HH 360
#define WW 480
#define NG 256
#define NPIX (HH * WW)
#define ALPHA_MIN (1.0f / 255.0f)
#define ALPHA_MAX 0.99f
#define TW 32            // tile width  -> 480/32 = 15 tiles
#define TH 8             // tile height -> 360/8  = 45 tiles
#define LOG2E 1.4426950408889634f

// ws layout (floats):
//   [   0..1024)  float4 q[256]    = (A, B, C, opacity)   log2-domain coeffs
//   [1024..2048)  float4 col[256]  = (r, g, b, depth)
//   [2048..2560)  float2 mean[256] = (mx, my)
//   [2560..3584)  float4 bbox[256] = (xlo, xhi, ylo, yhi)  alpha>=1/255 support
// Total 14336 bytes.

// ---------------------------------------------------------------------------
// Kernel 1: stable depth sort (rank count, N=256), precompute log2-domain
// quadratic coefficients and conservative support bbox, scatter sorted SoA.
// ---------------------------------------------------------------------------
__global__ __launch_bounds__(NG) void gs_sort_kernel(
    const float* __restrict__ md,      // (NG, 8)
    const float* __restrict__ means,   // (NG, 2)
    float* __restrict__ ws)
{
    __shared__ float sdep[NG];
    const int i = threadIdx.x;
    const float d = md[i * 8 + 7];
    sdep[i] = d;
    __syncthreads();

    int rank = 0;
    #pragma unroll 8
    for (int j = 0; j < NG; ++j) {
        const float dj = sdep[j];
        rank += (dj < d) || ((dj == d) && (j < i));
    }

    const float r  = md[i * 8 + 0];
    const float g  = md[i * 8 + 1];
    const float b  = md[i * 8 + 2];
    const float op = md[i * 8 + 3];
    const float ca = md[i * 8 + 4];
    const float cb = md[i * 8 + 5];
    const float cc = md[i * 8 + 6];
    const float mx = means[i * 2 + 0];
    const float my = means[i * 2 + 1];

    // log2 domain: alpha = op * 2^(-(A dx^2 + B dx dy + C dy^2))
    const float A = 0.5f * ca * LOG2E;
    const float B = cb * LOG2E;
    const float C = 0.5f * cc * LOG2E;

    // support: alpha >= 1/255  <=>  A dx^2 + B dx dy + C dy^2 <= log2(255*op)
    // ellipse bbox: dx_max^2 = 4*C*t / (4AC - B^2)   (pos. definite by ranges)
    const float t2   = __log2f(255.0f * op);
    const float det4 = 4.0f * A * C - B * B;
    const float dxm  = sqrtf(4.0f * C * t2 / det4) * 1.01f + 1.0f;  // slack
    const float dym  = sqrtf(4.0f * A * t2 / det4) * 1.01f + 1.0f;

    float4* q    = (float4*)(ws);
    float4* col  = (float4*)(ws + 1024);
    float2* mean = (float2*)(ws + 2048);
    float4* bbox = (float4*)(ws + 2560);
    q[rank]    = make_float4(A, B, C, op);
    col[rank]  = make_float4(r, g, b, d);
    mean[rank] = make_float2(mx, my);
    bbox[rank] = make_float4(mx - dxm, mx + dxm, my - dym, my + dym);
}

// ---------------------------------------------------------------------------
// Kernel 2: per-tile (32x8) rasterization. 256 threads cull 256 gaussians
// (bbox vs tile rect), ballot+prefix compaction preserving depth order into
// LDS SoA, then per-pixel composite over the short compacted list.
// Skipping a culled gaussian is exact: alpha < 1/255 -> 0 for every tile
// pixel, so it contributes nothing and leaves T unchanged.
// ---------------------------------------------------------------------------
__global__ __launch_bounds__(256) void gs_raster_kernel(
    const float* __restrict__ ws,
    float* __restrict__ out)
{
    __shared__ float4 sq[NG];
    __shared__ float4 scol[NG];
    __shared__ float2 smean[NG];
    __shared__ int    swcnt[4];

    const int t    = threadIdx.x;
    const int lane = t & 63;
    const int wv   = t >> 6;
    const int bx   = blockIdx.x;
    const int by   = blockIdx.y;

    // tile pixel-center bounds
    const float x0 = bx * TW + 0.5f;
    const float x1 = bx * TW + (TW - 1) + 0.5f;
    const float y0 = by * TH + 0.5f;
    const float y1 = by * TH + (TH - 1) + 0.5f;

    // cull: one gaussian per thread
    const float4 bb = ((const float4*)(ws + 2560))[t];
    const bool pred = (bb.y >= x0) & (bb.x <= x1) & (bb.w >= y0) & (bb.z <= y1);

    const unsigned long long mask = __ballot(pred);
    if (lane == 0) swcnt[wv] = __popcll(mask);
    __syncthreads();
    const int c0 = swcnt[0], c1 = swcnt[1], c2 = swcnt[2], c3 = swcnt[3];
    const int total = c0 + c1 + c2 + c3;
    int wofs = 0;
    if (wv > 0) wofs += c0;
    if (wv > 1) wofs += c1;
    if (wv > 2) wofs += c2;

    if (pred) {
        const int pos = wofs + __popcll(mask & ((1ull << lane) - 1ull));
        sq[pos]    = ((const float4*)(ws))[t];
        scol[pos]  = ((const float4*)(ws + 1024))[t];
        smean[pos] = ((const float2*)(ws + 2048))[t];
    }
    __syncthreads();

    const int tx = t & (TW - 1);
    const int ty = t >> 5;
    const float x = bx * TW + tx + 0.5f;
    const float y = by * TH + ty + 0.5f;

    float T = 1.0f;
    float accR = 0.0f, accG = 0.0f, accB = 0.0f, accD = 0.0f;

    for (int i = 0; i < total; ++i) {
        const float4 qq = sq[i];       // ds_read_b128, same-address broadcast
        const float2 mn = smean[i];
        const float dx = x - mn.x;
        const float dy = y - mn.y;
        float s = qq.x * dx * dx;
        s = __builtin_fmaf(qq.y, dx * dy, s);
        s = __builtin_fmaf(qq.z, dy * dy, s);
        float alpha = fminf(qq.w * __builtin_amdgcn_exp2f(-s), ALPHA_MAX);
        if (s < 0.0f) alpha = 0.0f;              // power > 0 case
        if (alpha < ALPHA_MIN) alpha = 0.0f;
        const float4 cl = scol[i];
        const float wgt = alpha * T;
        accR = __builtin_fmaf(wgt, cl.x, accR);
        accG = __builtin_fmaf(wgt, cl.y, accG);
        accB = __builtin_fmaf(wgt, cl.z, accB);
        accD = __builtin_fmaf(wgt, cl.w, accD);
        T = __builtin_fmaf(-alpha, T, T);        // T *= (1 - alpha)
    }

    const int p = (by * TH + ty) * WW + bx * TW + tx;
    out[p * 3 + 0]    = accR;
    out[p * 3 + 1]    = accG;
    out[p * 3 + 2]    = accB;
    out[NPIX * 3 + p] = accD;
    out[NPIX * 4 + p] = 1.0f - T;
}

extern "C" void kernel_launch(void* const* d_in, const int* in_sizes, int n_in,
                              void* d_out, int out_size, void* d_ws, size_t ws_size,
                              hipStream_t stream) {
    const float* md    = (const float*)d_in[0];   // md_1_for (256,8)
    const float* means = (const float*)d_in[1];   // means2D  (256,2)
    float* out = (float*)d_out;
    float* ws  = (float*)d_ws;                    // needs 14336 B

    gs_sort_kernel<<<1, NG, 0, stream>>>(md, means, ws);
    gs_raster_kernel<<<dim3(WW / TW, HH / TH), 256, 0, stream>>>(ws, out);
}

// Round 3
// 17.226 us; speedup vs baseline: 3.7069x; 1.0036x over previous
//
#include <hip/hip_runtime.h>

#define HH 360
#define WW 480
#define NG 256
#define NPIX (HH * WW)
#define ALPHA_MIN (1.0f / 255.0f)
#define ALPHA_MAX 0.99f
#define TW 32            // 480/32 = 15 tiles
#define TH 8             // 360/8  = 45 tiles
#define LOG2E 1.4426950408889634f

// ---------------------------------------------------------------------------
// Single fused kernel, one block = one 32x8 tile, one thread = one pixel AND
// one gaussian (NG == blockDim == 256).
//   1. thread t loads gaussian t, computes log2-domain coeffs + support bbox
//   2. cull vs tile rect; ballot+prefix compaction of survivor DEPTHS into
//      LDS (compacted position preserves original index order = stable
//      argsort tiebreak)
//   3. each survivor ranks itself among the K survivors (K-iter broadcast
//      loop, K ~ 10-30) and scatters its registers into depth-ordered LDS SoA
//   4. per-pixel front-to-back composite over the ordered list
// Culling is exact: a culled gaussian has alpha < 1/255 at every pixel center
// of the tile -> contributes 0 and leaves T unchanged.
// ---------------------------------------------------------------------------
__global__ __launch_bounds__(256) void gs_fused_kernel(
    const float* __restrict__ md,      // (NG, 8) r,g,b,op,ca,cb,cc,depth
    const float* __restrict__ means,   // (NG, 2)
    float* __restrict__ out)
{
    __shared__ float4 sq[NG];      // (A, B, C, opacity) depth-ordered
    __shared__ float4 scol[NG];    // (r, g, b, depth)
    __shared__ float2 smean[NG];   // (mx, my)
    __shared__ float  sdep[NG];    // survivor depths, compacted order
    __shared__ int    swcnt[4];

    const int t    = threadIdx.x;
    const int lane = t & 63;
    const int wv   = t >> 6;
    const int bx   = blockIdx.x;
    const int by   = blockIdx.y;

    // ---- load gaussian t, precompute in registers ----
    const float4 m0 = ((const float4*)md)[2 * t];       // r,g,b,op
    const float4 m1 = ((const float4*)md)[2 * t + 1];   // ca,cb,cc,depth
    const float2 mn = ((const float2*)means)[t];

    // alpha = op * 2^-(A dx^2 + B dx dy + C dy^2)
    const float A = 0.5f * LOG2E * m1.x;
    const float B = LOG2E * m1.y;
    const float C = 0.5f * LOG2E * m1.z;

    // support bbox of alpha >= 1/255 (ellipse, pos.definite by input ranges)
    const float t2   = __log2f(255.0f * m0.w);
    const float det4 = 4.0f * A * C - B * B;
    const float s4   = 4.0f * t2 / det4;
    const float dxm  = sqrtf(C * s4) * 1.01f + 1.0f;
    const float dym  = sqrtf(A * s4) * 1.01f + 1.0f;

    // ---- cull vs tile pixel-center rect ----
    const float x0 = bx * TW + 0.5f, x1 = bx * TW + (TW - 1) + 0.5f;
    const float y0 = by * TH + 0.5f, y1 = by * TH + (TH - 1) + 0.5f;
    const bool pred = (mn.x + dxm >= x0) & (mn.x - dxm <= x1) &
                      (mn.y + dym >= y0) & (mn.y - dym <= y1);

    const unsigned long long mask = __ballot(pred);
    if (lane == 0) swcnt[wv] = __popcll(mask);
    __syncthreads();
    const int c0 = swcnt[0], c1 = swcnt[1], c2 = swcnt[2], c3 = swcnt[3];
    const int total = c0 + c1 + c2 + c3;
    int wofs = 0;
    if (wv > 0) wofs += c0;
    if (wv > 1) wofs += c1;
    if (wv > 2) wofs += c2;

    int pos = 0;
    if (pred) {
        pos = wofs + __popcll(mask & ((1ull << lane) - 1ull));
        sdep[pos] = m1.w;
    }
    __syncthreads();

    // ---- rank among survivors (stable: tiebreak by compacted position,
    //      which is increasing in original index), scatter registers ----
    if (pred) {
        const float d = m1.w;
        int rank = 0;
        for (int j = 0; j < total; ++j) {
            const float dj = sdep[j];
            rank += (dj < d) || ((dj == d) && (j < pos));
        }
        sq[rank]    = make_float4(A, B, C, m0.w);
        scol[rank]  = make_float4(m0.x, m0.y, m0.z, m1.w);
        smean[rank] = mn;
    }
    __syncthreads();

    // ---- per-pixel composite ----
    const int tx = t & (TW - 1);
    const int ty = t >> 5;
    const float x = bx * TW + tx + 0.5f;
    const float y = by * TH + ty + 0.5f;

    float T = 1.0f;
    float accR = 0.0f, accG = 0.0f, accB = 0.0f, accD = 0.0f;

    for (int i = 0; i < total; ++i) {
        const float4 qq = sq[i];        // same-address LDS broadcast
        const float2 c  = smean[i];
        const float dx = x - c.x;
        const float dy = y - c.y;
        float s = qq.x * dx * dx;
        s = __builtin_fmaf(qq.y, dx * dy, s);
        s = __builtin_fmaf(qq.z, dy * dy, s);
        float alpha = fminf(qq.w * __builtin_amdgcn_exp2f(-s), ALPHA_MAX);
        if (s < 0.0f) alpha = 0.0f;     // power > 0 case
        if (alpha < ALPHA_MIN) alpha = 0.0f;
        const float4 cl = scol[i];
        const float wgt = alpha * T;
        accR = __builtin_fmaf(wgt, cl.x, accR);
        accG = __builtin_fmaf(wgt, cl.y, accG);
        accB = __builtin_fmaf(wgt, cl.z, accB);
        accD = __builtin_fmaf(wgt, cl.w, accD);
        T = __builtin_fmaf(-alpha, T, T);
    }

    const int p = (by * TH + ty) * WW + bx * TW + tx;
    out[p * 3 + 0]    = accR;
    out[p * 3 + 1]    = accG;
    out[p * 3 + 2]    = accB;
    out[NPIX * 3 + p] = accD;
    out[NPIX * 4 + p] = 1.0f - T;
}

extern "C" void kernel_launch(void* const* d_in, const int* in_sizes, int n_in,
                              void* d_out, int out_size, void* d_ws, size_t ws_size,
                              hipStream_t stream) {
    const float* md    = (const float*)d_in[0];
    const float* means = (const float*)d_in[1];
    float* out = (float*)d_out;
    (void)d_ws; (void)ws_size;

    gs_fused_kernel<<<dim3(WW / TW, HH / TH), 256, 0, stream>>>(md, means, out);
}

// Round 4
// 11.382 us; speedup vs baseline: 5.6099x; 1.5134x over previous
//
#include <hip/hip_runtime.h>

#define HH 360
#define WW 480
#define NG 256
#define NPIX (HH * WW)
#define ALPHA_MIN (1.0f / 255.0f)
#define ALPHA_MAX 0.99f
#define TW 32            // 480/32 = 15 tiles
#define TH 24            // 360/24 = 15 tiles -> 225 blocks, 1 per CU
#define PPT 3            // pixels per thread (rows ty, ty+8, ty+16)
#define LOG2E 1.4426950408889634f

struct Float3 { float x, y, z; };

// ---------------------------------------------------------------------------
// One block = one 32x24 tile (225 blocks -> single occupancy round on 256
// CUs). One thread = one gaussian (cull/rank phase) AND 3 pixels (composite).
//   1. thread t loads gaussian t, computes log2-domain coeffs + support bbox
//   2. cull vs tile rect; ballot+prefix compaction of survivor depths into
//      LDS (compacted position preserves original-index order = stable tie)
//   3. survivors rank themselves among the K survivors (K ~ 12) and scatter
//      registers into depth-ordered LDS SoA
//   4. each thread composites 3 pixels (independent chains -> ILP)
// Culling is exact: culled gaussian has alpha < 1/255 at every tile pixel.
// ---------------------------------------------------------------------------
__global__ __launch_bounds__(256) void gs_fused_kernel(
    const float* __restrict__ md,      // (NG, 8) r,g,b,op,ca,cb,cc,depth
    const float* __restrict__ means,   // (NG, 2)
    float* __restrict__ out)
{
    __shared__ float4 sq[NG];      // (A, B, C, opacity) depth-ordered
    __shared__ float4 scol[NG];    // (r, g, b, depth)
    __shared__ float2 smean[NG];   // (mx, my)
    __shared__ float  sdep[NG];    // survivor depths, compacted order
    __shared__ int    swcnt[4];

    const int t    = threadIdx.x;
    const int lane = t & 63;
    const int wv   = t >> 6;
    const int bx   = blockIdx.x;
    const int by   = blockIdx.y;

    // ---- load gaussian t, precompute in registers ----
    const float4 m0 = ((const float4*)md)[2 * t];       // r,g,b,op
    const float4 m1 = ((const float4*)md)[2 * t + 1];   // ca,cb,cc,depth
    const float2 mn = ((const float2*)means)[t];

    // alpha = op * 2^-(A dx^2 + B dx dy + C dy^2)
    const float A = 0.5f * LOG2E * m1.x;
    const float B = LOG2E * m1.y;
    const float C = 0.5f * LOG2E * m1.z;

    // support bbox of alpha >= 1/255 (ellipse; pos.definite by input ranges)
    const float t2   = __log2f(255.0f * m0.w);
    const float det4 = 4.0f * A * C - B * B;
    const float s4   = 4.0f * t2 / det4;
    const float dxm  = sqrtf(C * s4) * 1.01f + 1.0f;
    const float dym  = sqrtf(A * s4) * 1.01f + 1.0f;

    // ---- cull vs tile pixel-center rect ----
    const float x0 = bx * TW + 0.5f, x1 = bx * TW + (TW - 1) + 0.5f;
    const float y0 = by * TH + 0.5f, y1 = by * TH + (TH - 1) + 0.5f;
    const bool pred = (mn.x + dxm >= x0) & (mn.x - dxm <= x1) &
                      (mn.y + dym >= y0) & (mn.y - dym <= y1);

    const unsigned long long mask = __ballot(pred);
    if (lane == 0) swcnt[wv] = __popcll(mask);
    __syncthreads();
    const int c0 = swcnt[0], c1 = swcnt[1], c2 = swcnt[2], c3 = swcnt[3];
    const int total = c0 + c1 + c2 + c3;
    int wofs = 0;
    if (wv > 0) wofs += c0;
    if (wv > 1) wofs += c1;
    if (wv > 2) wofs += c2;

    int pos = 0;
    if (pred) {
        pos = wofs + __popcll(mask & ((1ull << lane) - 1ull));
        sdep[pos] = m1.w;
    }
    __syncthreads();

    // ---- rank among survivors (stable), scatter registers ----
    if (pred) {
        const float d = m1.w;
        int rank = 0;
        for (int j = 0; j < total; ++j) {
            const float dj = sdep[j];
            rank += (dj < d) || ((dj == d) && (j < pos));
        }
        sq[rank]    = make_float4(A, B, C, m0.w);
        scol[rank]  = make_float4(m0.x, m0.y, m0.z, m1.w);
        smean[rank] = mn;
    }
    __syncthreads();

    // ---- composite: 3 pixels per thread (rows ty, ty+8, ty+16) ----
    const int tx = t & (TW - 1);
    const int ty = t >> 5;                 // 0..7
    const float x = bx * TW + tx + 0.5f;
    const float yb = by * TH + ty + 0.5f;  // +0, +8, +16

    float T0 = 1.0f, T1 = 1.0f, T2 = 1.0f;
    float r0 = 0, g0 = 0, b0 = 0, d0 = 0;
    float r1 = 0, g1 = 0, b1 = 0, d1 = 0;
    float r2 = 0, g2 = 0, b2 = 0, d2 = 0;

    #pragma unroll 2
    for (int i = 0; i < total; ++i) {
        const float4 qq = sq[i];        // same-address LDS broadcast
        const float2 c  = smean[i];
        const float4 cl = scol[i];
        const float dx  = x - c.x;
        const float dxq = qq.y * dx;            // B*dx (shared)
        const float sxx = qq.x * dx * dx;       // A*dx^2 (shared)

        const float dy0 = yb - c.y;
        const float dy1 = dy0 + 8.0f;
        const float dy2 = dy0 + 16.0f;

        float s0 = __builtin_fmaf(qq.z, dy0 * dy0, __builtin_fmaf(dxq, dy0, sxx));
        float s1 = __builtin_fmaf(qq.z, dy1 * dy1, __builtin_fmaf(dxq, dy1, sxx));
        float s2 = __builtin_fmaf(qq.z, dy2 * dy2, __builtin_fmaf(dxq, dy2, sxx));

        float a0 = fminf(qq.w * __builtin_amdgcn_exp2f(-s0), ALPHA_MAX);
        float a1 = fminf(qq.w * __builtin_amdgcn_exp2f(-s1), ALPHA_MAX);
        float a2 = fminf(qq.w * __builtin_amdgcn_exp2f(-s2), ALPHA_MAX);
        if ((s0 < 0.0f) | (a0 < ALPHA_MIN)) a0 = 0.0f;
        if ((s1 < 0.0f) | (a1 < ALPHA_MIN)) a1 = 0.0f;
        if ((s2 < 0.0f) | (a2 < ALPHA_MIN)) a2 = 0.0f;

        const float w0 = a0 * T0, w1 = a1 * T1, w2 = a2 * T2;
        r0 = __builtin_fmaf(w0, cl.x, r0); r1 = __builtin_fmaf(w1, cl.x, r1); r2 = __builtin_fmaf(w2, cl.x, r2);
        g0 = __builtin_fmaf(w0, cl.y, g0); g1 = __builtin_fmaf(w1, cl.y, g1); g2 = __builtin_fmaf(w2, cl.y, g2);
        b0 = __builtin_fmaf(w0, cl.z, b0); b1 = __builtin_fmaf(w1, cl.z, b1); b2 = __builtin_fmaf(w2, cl.z, b2);
        d0 = __builtin_fmaf(w0, cl.w, d0); d1 = __builtin_fmaf(w1, cl.w, d1); d2 = __builtin_fmaf(w2, cl.w, d2);
        T0 = __builtin_fmaf(-a0, T0, T0);
        T1 = __builtin_fmaf(-a1, T1, T1);
        T2 = __builtin_fmaf(-a2, T2, T2);
    }

    // ---- stores: color as one dwordx3 per pixel, depth/sil coalesced ----
    const int row0 = by * TH + ty;
    const int p0 = row0 * WW + bx * TW + tx;
    const int p1 = p0 + 8 * WW;
    const int p2 = p0 + 16 * WW;

    *(Float3*)&out[p0 * 3] = {r0, g0, b0};
    *(Float3*)&out[p1 * 3] = {r1, g1, b1};
    *(Float3*)&out[p2 * 3] = {r2, g2, b2};
    out[NPIX * 3 + p0] = d0;
    out[NPIX * 3 + p1] = d1;
    out[NPIX * 3 + p2] = d2;
    out[NPIX * 4 + p0] = 1.0f - T0;
    out[NPIX * 4 + p1] = 1.0f - T1;
    out[NPIX * 4 + p2] = 1.0f - T2;
}

extern "C" void kernel_launch(void* const* d_in, const int* in_sizes, int n_in,
                              void* d_out, int out_size, void* d_ws, size_t ws_size,
                              hipStream_t stream) {
    const float* md    = (const float*)d_in[0];
    const float* means = (const float*)d_in[1];
    float* out = (float*)d_out;
    (void)d_ws; (void)ws_size;

    gs_fused_kernel<<<dim3(WW / TW, HH / TH), 256, 0, stream>>>(md, means, out);
}